// Round 1
// baseline (3702.877 us; speedup 1.0000x reference)
//
#include <hip/hip_runtime.h>
#include <stdint.h>

// Problem dims (fixed by reference)
#define MB_ 2
#define LL_ 2048
#define M_ (MB_*LL_)   // 4096 tokens
#define H_ 4096
#define I_ 11008

// Tile config
#define TM 128
#define TN 128
#define BK 32
#define LDK 40   // padded LDS row stride in bf16 elems (80 B = 20 banks -> worst 2-way, free)

static_assert(M_ % TM == 0, "");
static_assert(I_ % TN == 0, "");
static_assert(H_ % TN == 0, "");
static_assert(H_ % BK == 0, "");
static_assert(I_ % BK == 0, "");

typedef __attribute__((ext_vector_type(8))) short bf16x8;
typedef __attribute__((ext_vector_type(4))) float f32x4;
typedef __attribute__((ext_vector_type(4))) unsigned short us4;

__device__ __forceinline__ unsigned short f2bf(float f) {
  union { float f; unsigned int u; } v; v.f = f;
  unsigned int r = v.u + 0x7FFFu + ((v.u >> 16) & 1u);  // RNE
  return (unsigned short)(r >> 16);
}

// ---------------------------------------------------------------------------
// Kernel 1: fused up/gate GEMM.  h[m,i] = up[m,i] * silu(gate[m,i]) * mask[m]
// A = hs [M,H] fp32 row-major; Wu,Wg = [I,H] fp32 row-major (NT GEMM).
// Output h as bf16 [M,I] into workspace.
// ---------------------------------------------------------------------------
__global__ __launch_bounds__(256)
void mlp_upgate(const float* __restrict__ hs, const float* __restrict__ wu,
                const float* __restrict__ wg, const int* __restrict__ mask,
                unsigned short* __restrict__ hbuf)
{
  __shared__ unsigned short As[TM * LDK];
  __shared__ unsigned short Bu[TN * LDK];
  __shared__ unsigned short Bg[TN * LDK];
  __shared__ float smask[TM];

  const int tid = threadIdx.x;
  const int m0 = blockIdx.x * TM;   // 32 tiles
  const int n0 = blockIdx.y * TN;   // 86 tiles

  if (tid < TM) smask[tid] = (float)mask[m0 + tid];

  const int wave = tid >> 6;
  const int lane = tid & 63;
  const int quad = lane >> 4;
  const int rrow = lane & 15;
  const int wm = (wave & 1) * 64;
  const int wn = (wave >> 1) * 64;

  f32x4 accU[4][4], accG[4][4];
  const f32x4 zero = {0.f, 0.f, 0.f, 0.f};
  for (int i = 0; i < 4; i++)
    for (int j = 0; j < 4; j++) { accU[i][j] = zero; accG[i][j] = zero; }

  for (int k0 = 0; k0 < H_; k0 += BK) {
    // ---- stage A, Bu, Bg tiles (fp32 -> bf16 in-register) ----
#pragma unroll
    for (int s = 0; s < 4; s++) {
      int idx = tid + s * 256;          // 0..1023
      int row = idx >> 3;               // 0..127
      int c4  = (idx & 7) * 4;          // 0..28
      float4 a = *(const float4*)&hs[(size_t)(m0 + row) * H_ + k0 + c4];
      float4 u = *(const float4*)&wu[(size_t)(n0 + row) * H_ + k0 + c4];
      float4 g = *(const float4*)&wg[(size_t)(n0 + row) * H_ + k0 + c4];
      us4 av = { f2bf(a.x), f2bf(a.y), f2bf(a.z), f2bf(a.w) };
      us4 uv = { f2bf(u.x), f2bf(u.y), f2bf(u.z), f2bf(u.w) };
      us4 gv = { f2bf(g.x), f2bf(g.y), f2bf(g.z), f2bf(g.w) };
      *(us4*)&As[row * LDK + c4] = av;
      *(us4*)&Bu[row * LDK + c4] = uv;
      *(us4*)&Bg[row * LDK + c4] = gv;
    }
    __syncthreads();

    // ---- fragments + MFMA ----
    bf16x8 af[4], bu[4], bg[4];
#pragma unroll
    for (int mi = 0; mi < 4; mi++)
      af[mi] = *(const bf16x8*)&As[(wm + mi * 16 + rrow) * LDK + quad * 8];
#pragma unroll
    for (int ni = 0; ni < 4; ni++) {
      bu[ni] = *(const bf16x8*)&Bu[(wn + ni * 16 + rrow) * LDK + quad * 8];
      bg[ni] = *(const bf16x8*)&Bg[(wn + ni * 16 + rrow) * LDK + quad * 8];
    }
#pragma unroll
    for (int mi = 0; mi < 4; mi++)
#pragma unroll
      for (int ni = 0; ni < 4; ni++) {
        accU[mi][ni] = __builtin_amdgcn_mfma_f32_16x16x32_bf16(af[mi], bu[ni], accU[mi][ni], 0, 0, 0);
        accG[mi][ni] = __builtin_amdgcn_mfma_f32_16x16x32_bf16(af[mi], bg[ni], accG[mi][ni], 0, 0, 0);
      }
    __syncthreads();
  }

  // ---- epilogue: h = up * silu(gate) * mask, store bf16 ----
  // C/D layout (verified m89/m91): col = lane&15, row = (lane>>4)*4 + reg
#pragma unroll
  for (int mi = 0; mi < 4; mi++)
#pragma unroll
    for (int ni = 0; ni < 4; ni++)
#pragma unroll
      for (int r = 0; r < 4; r++) {
        int row = wm + mi * 16 + quad * 4 + r;
        int col = wn + ni * 16 + rrow;
        float u = accU[mi][ni][r];
        float g = accG[mi][ni][r];
        float sig = 1.0f / (1.0f + __expf(-g));
        float h = u * g * sig * smask[row];
        hbuf[(size_t)(m0 + row) * I_ + n0 + col] = f2bf(h);
      }
}

// ---------------------------------------------------------------------------
// Kernel 2: down GEMM. out[m,n] = sum_i h[m,i] * wd[n,i]   (NT GEMM)
// A = h bf16 [M,I]; B = wd fp32 [H,I] converted on the fly. Output fp32.
// ---------------------------------------------------------------------------
__global__ __launch_bounds__(256)
void mlp_down(const unsigned short* __restrict__ hbuf,
              const float* __restrict__ wd, float* __restrict__ out)
{
  __shared__ unsigned short As[TM * LDK];
  __shared__ unsigned short Bs[TN * LDK];

  const int tid = threadIdx.x;
  const int m0 = blockIdx.x * TM;   // 32 tiles
  const int n0 = blockIdx.y * TN;   // 32 tiles

  const int wave = tid >> 6;
  const int lane = tid & 63;
  const int quad = lane >> 4;
  const int rrow = lane & 15;
  const int wm = (wave & 1) * 64;
  const int wn = (wave >> 1) * 64;

  f32x4 acc[4][4];
  const f32x4 zero = {0.f, 0.f, 0.f, 0.f};
  for (int i = 0; i < 4; i++)
    for (int j = 0; j < 4; j++) acc[i][j] = zero;

  for (int k0 = 0; k0 < I_; k0 += BK) {
#pragma unroll
    for (int s = 0; s < 4; s++) {
      int idx = tid + s * 256;
      int row = idx >> 3;
      int c4  = (idx & 7) * 4;
      us4 av = *(const us4*)&hbuf[(size_t)(m0 + row) * I_ + k0 + c4];  // already bf16
      float4 b = *(const float4*)&wd[(size_t)(n0 + row) * I_ + k0 + c4];
      us4 bv = { f2bf(b.x), f2bf(b.y), f2bf(b.z), f2bf(b.w) };
      *(us4*)&As[row * LDK + c4] = av;
      *(us4*)&Bs[row * LDK + c4] = bv;
    }
    __syncthreads();

    bf16x8 af[4], bf[4];
#pragma unroll
    for (int mi = 0; mi < 4; mi++)
      af[mi] = *(const bf16x8*)&As[(wm + mi * 16 + rrow) * LDK + quad * 8];
#pragma unroll
    for (int ni = 0; ni < 4; ni++)
      bf[ni] = *(const bf16x8*)&Bs[(wn + ni * 16 + rrow) * LDK + quad * 8];
#pragma unroll
    for (int mi = 0; mi < 4; mi++)
#pragma unroll
      for (int ni = 0; ni < 4; ni++)
        acc[mi][ni] = __builtin_amdgcn_mfma_f32_16x16x32_bf16(af[mi], bf[ni], acc[mi][ni], 0, 0, 0);
    __syncthreads();
  }

#pragma unroll
  for (int mi = 0; mi < 4; mi++)
#pragma unroll
    for (int ni = 0; ni < 4; ni++)
#pragma unroll
      for (int r = 0; r < 4; r++) {
        int row = wm + mi * 16 + quad * 4 + r;
        int col = wn + ni * 16 + rrow;
        out[(size_t)(m0 + row) * H_ + n0 + col] = acc[mi][ni][r];
      }
}

// ---------------------------------------------------------------------------
extern "C" void kernel_launch(void* const* d_in, const int* in_sizes, int n_in,
                              void* d_out, int out_size, void* d_ws, size_t ws_size,
                              hipStream_t stream) {
  const float* hs  = (const float*)d_in[0];   // [2,2048,4096] fp32
  const float* wu  = (const float*)d_in[1];   // [11008,4096] fp32
  const float* wg  = (const float*)d_in[2];   // [11008,4096] fp32
  const float* wd  = (const float*)d_in[3];   // [4096,11008] fp32
  const int*   msk = (const int*)d_in[4];     // [2,2048] int32
  float* out = (float*)d_out;                 // [2,2048,4096] fp32
  unsigned short* hbuf = (unsigned short*)d_ws;  // bf16 [4096,11008] = 90.2 MB

  dim3 g1(M_ / TM, I_ / TN);   // 32 x 86
  mlp_upgate<<<g1, dim3(256), 0, stream>>>(hs, wu, wg, msk, hbuf);

  dim3 g2(M_ / TM, H_ / TN);   // 32 x 32
  mlp_down<<<g2, dim3(256), 0, stream>>>(hbuf, wd, out);
}

// Round 2
// 1952.130 us; speedup vs baseline: 1.8968x; 1.8968x over previous
//
#include <hip/hip_runtime.h>
#include <stdint.h>

// Problem dims (fixed by reference)
#define MB_ 2
#define LL_ 2048
#define M_ (MB_*LL_)   // 4096 tokens
#define H_ 4096
#define I_ 11008

typedef __attribute__((ext_vector_type(8))) short bf16x8;
typedef __attribute__((ext_vector_type(4))) float f32x4;
typedef __attribute__((ext_vector_type(4))) unsigned short us4;

__device__ __forceinline__ unsigned short f2bf(float f) {
  union { float f; unsigned int u; } v; v.f = f;
  unsigned int r = v.u + 0x7FFFu + ((v.u >> 16) & 1u);  // RNE
  return (unsigned short)(r >> 16);
}

__device__ __forceinline__ void gl2lds16(const void* g, void* l) {
  __builtin_amdgcn_global_load_lds(
      (const __attribute__((address_space(1))) void*)g,
      (__attribute__((address_space(3))) void*)l, 16, 0, 0);
}

// ---------------------------------------------------------------------------
// fp32 -> bf16 bulk conversion (8 elems / thread)
// ---------------------------------------------------------------------------
__global__ __launch_bounds__(256)
void cvt_bf16(const float* __restrict__ src, unsigned short* __restrict__ dst, int n8) {
  int i = blockIdx.x * blockDim.x + threadIdx.x;
  if (i >= n8) return;
  const float4* s = (const float4*)src + (size_t)i * 2;
  float4 a = s[0], b = s[1];
  us4 lo = { f2bf(a.x), f2bf(a.y), f2bf(a.z), f2bf(a.w) };
  us4 hi = { f2bf(b.x), f2bf(b.y), f2bf(b.z), f2bf(b.w) };
  us4* d = (us4*)dst + (size_t)i * 2;
  d[0] = lo; d[1] = hi;
}

// ---------------------------------------------------------------------------
// GEMM1 (m97-style): h[m,i] = up * silu(gate) * mask.  All-bf16 inputs.
// Block tile: M=128, N=64 (dual: up+gate). BK=32. 4 waves, each 64x32 per mat.
// LDS staged via global_load_lds width-16 (no padding, contiguous layout).
// ---------------------------------------------------------------------------
__global__ __launch_bounds__(256)
void mlp_upgate2(const unsigned short* __restrict__ hs16,
                 const unsigned short* __restrict__ wu16,
                 const unsigned short* __restrict__ wg16,
                 const int* __restrict__ mask,
                 unsigned short* __restrict__ hbuf)
{
  __shared__ unsigned short As[128 * 32];
  __shared__ unsigned short Bu[64 * 32];
  __shared__ unsigned short Bg[64 * 32];
  __shared__ float smask[128];

  const int tid  = threadIdx.x;
  const int m0   = blockIdx.x * 128;  // 32
  const int n0   = blockIdx.y * 64;   // 172
  const int w    = tid >> 6;
  const int lane = tid & 63;
  const int quad = lane >> 4;
  const int rrow = lane & 15;
  const int wm   = (w & 1) * 64;
  const int wn   = (w >> 1) * 32;

  if (tid < 128) smask[tid] = (float)mask[m0 + tid];

  // staging source pointers (elems); advance by BK per iter
  const int lr = lane >> 2;        // 0..15 row within 16-row group
  const int lc = (lane & 3) * 8;   // 0..24 col elem
  const unsigned short* pa0 = hs16 + (size_t)(m0 + w * 32 + lr) * H_ + lc;
  const unsigned short* pa1 = pa0 + (size_t)16 * H_;
  const unsigned short* pu  = wu16 + (size_t)(n0 + w * 16 + lr) * H_ + lc;
  const unsigned short* pg  = wg16 + (size_t)(n0 + w * 16 + lr) * H_ + lc;
  // wave-uniform LDS destinations
  unsigned short* la0 = &As[(w * 32) * 32];
  unsigned short* la1 = &As[(w * 32 + 16) * 32];
  unsigned short* lu  = &Bu[(w * 16) * 32];
  unsigned short* lg  = &Bg[(w * 16) * 32];

  f32x4 accU[4][2], accG[4][2];
  const f32x4 zero = {0.f, 0.f, 0.f, 0.f};
  for (int i = 0; i < 4; i++)
    for (int j = 0; j < 2; j++) { accU[i][j] = zero; accG[i][j] = zero; }

  for (int k0 = 0; k0 < H_; k0 += 32) {
    gl2lds16(pa0 + k0, la0);
    gl2lds16(pa1 + k0, la1);
    gl2lds16(pu + k0, lu);
    gl2lds16(pg + k0, lg);
    __syncthreads();

    bf16x8 af[4], bu[2], bg[2];
#pragma unroll
    for (int mi = 0; mi < 4; mi++)
      af[mi] = *(const bf16x8*)&As[(wm + mi * 16 + rrow) * 32 + quad * 8];
#pragma unroll
    for (int ni = 0; ni < 2; ni++) {
      bu[ni] = *(const bf16x8*)&Bu[(wn + ni * 16 + rrow) * 32 + quad * 8];
      bg[ni] = *(const bf16x8*)&Bg[(wn + ni * 16 + rrow) * 32 + quad * 8];
    }
#pragma unroll
    for (int mi = 0; mi < 4; mi++)
#pragma unroll
      for (int ni = 0; ni < 2; ni++) {
        accU[mi][ni] = __builtin_amdgcn_mfma_f32_16x16x32_bf16(af[mi], bu[ni], accU[mi][ni], 0, 0, 0);
        accG[mi][ni] = __builtin_amdgcn_mfma_f32_16x16x32_bf16(af[mi], bg[ni], accG[mi][ni], 0, 0, 0);
      }
    __syncthreads();
  }

  // epilogue: C/D layout col=lane&15, row=quad*4+reg (verified m89/m91)
#pragma unroll
  for (int mi = 0; mi < 4; mi++)
#pragma unroll
    for (int ni = 0; ni < 2; ni++)
#pragma unroll
      for (int r = 0; r < 4; r++) {
        int row = wm + mi * 16 + quad * 4 + r;
        int col = wn + ni * 16 + rrow;
        float u = accU[mi][ni][r];
        float g = accG[mi][ni][r];
        float sig = 1.0f / (1.0f + __expf(-g));
        float h = u * g * sig * smask[row];
        hbuf[(size_t)(m0 + row) * I_ + n0 + col] = f2bf(h);
      }
}

// ---------------------------------------------------------------------------
// GEMM2 (m97): out[m,n] = sum_i h[m,i] * wd[n,i], bf16 inputs, fp32 out.
// Block tile 128x128, BK=32, 4 waves 2x2, each 64x64 (4x4 frags).
// ---------------------------------------------------------------------------
__global__ __launch_bounds__(256)
void mlp_down2(const unsigned short* __restrict__ hbuf,
               const unsigned short* __restrict__ wd16,
               float* __restrict__ out)
{
  __shared__ unsigned short As[128 * 32];
  __shared__ unsigned short Bs[128 * 32];

  const int tid  = threadIdx.x;
  const int m0   = blockIdx.x * 128;  // 32
  const int n0   = blockIdx.y * 128;  // 32
  const int w    = tid >> 6;
  const int lane = tid & 63;
  const int quad = lane >> 4;
  const int rrow = lane & 15;
  const int wm   = (w & 1) * 64;
  const int wn   = (w >> 1) * 64;

  const int lr = lane >> 2;
  const int lc = (lane & 3) * 8;
  const unsigned short* pa0 = hbuf + (size_t)(m0 + w * 32 + lr) * I_ + lc;
  const unsigned short* pa1 = pa0 + (size_t)16 * I_;
  const unsigned short* pb0 = wd16 + (size_t)(n0 + w * 32 + lr) * I_ + lc;
  const unsigned short* pb1 = pb0 + (size_t)16 * I_;
  unsigned short* la0 = &As[(w * 32) * 32];
  unsigned short* la1 = &As[(w * 32 + 16) * 32];
  unsigned short* lb0 = &Bs[(w * 32) * 32];
  unsigned short* lb1 = &Bs[(w * 32 + 16) * 32];

  f32x4 acc[4][4];
  const f32x4 zero = {0.f, 0.f, 0.f, 0.f};
  for (int i = 0; i < 4; i++)
    for (int j = 0; j < 4; j++) acc[i][j] = zero;

  for (int k0 = 0; k0 < I_; k0 += 32) {
    gl2lds16(pa0 + k0, la0);
    gl2lds16(pa1 + k0, la1);
    gl2lds16(pb0 + k0, lb0);
    gl2lds16(pb1 + k0, lb1);
    __syncthreads();

    bf16x8 af[4], bf[4];
#pragma unroll
    for (int mi = 0; mi < 4; mi++)
      af[mi] = *(const bf16x8*)&As[(wm + mi * 16 + rrow) * 32 + quad * 8];
#pragma unroll
    for (int ni = 0; ni < 4; ni++)
      bf[ni] = *(const bf16x8*)&Bs[(wn + ni * 16 + rrow) * 32 + quad * 8];
#pragma unroll
    for (int mi = 0; mi < 4; mi++)
#pragma unroll
      for (int ni = 0; ni < 4; ni++)
        acc[mi][ni] = __builtin_amdgcn_mfma_f32_16x16x32_bf16(af[mi], bf[ni], acc[mi][ni], 0, 0, 0);
    __syncthreads();
  }

#pragma unroll
  for (int mi = 0; mi < 4; mi++)
#pragma unroll
    for (int ni = 0; ni < 4; ni++)
#pragma unroll
      for (int r = 0; r < 4; r++) {
        int row = wm + mi * 16 + quad * 4 + r;
        int col = wn + ni * 16 + rrow;
        out[(size_t)(m0 + row) * H_ + n0 + col] = acc[mi][ni][r];
      }
}

// ===========================================================================
// Fallback path (round-1 kernels) if ws_size is too small for bf16 weights.
// ===========================================================================
#define TM 128
#define TN 128
#define BK 32
#define LDK 40

__global__ __launch_bounds__(256)
void mlp_upgate_fb(const float* __restrict__ hs, const float* __restrict__ wu,
                   const float* __restrict__ wg, const int* __restrict__ mask,
                   unsigned short* __restrict__ hbuf)
{
  __shared__ unsigned short As[TM * LDK];
  __shared__ unsigned short Bu[TN * LDK];
  __shared__ unsigned short Bg[TN * LDK];
  __shared__ float smask[TM];

  const int tid = threadIdx.x;
  const int m0 = blockIdx.x * TM;
  const int n0 = blockIdx.y * TN;
  if (tid < TM) smask[tid] = (float)mask[m0 + tid];
  const int wave = tid >> 6, lane = tid & 63;
  const int quad = lane >> 4, rrow = lane & 15;
  const int wm = (wave & 1) * 64, wn = (wave >> 1) * 64;

  f32x4 accU[4][4], accG[4][4];
  const f32x4 zero = {0.f, 0.f, 0.f, 0.f};
  for (int i = 0; i < 4; i++)
    for (int j = 0; j < 4; j++) { accU[i][j] = zero; accG[i][j] = zero; }

  for (int k0 = 0; k0 < H_; k0 += BK) {
#pragma unroll
    for (int s = 0; s < 4; s++) {
      int idx = tid + s * 256, row = idx >> 3, c4 = (idx & 7) * 4;
      float4 a = *(const float4*)&hs[(size_t)(m0 + row) * H_ + k0 + c4];
      float4 u = *(const float4*)&wu[(size_t)(n0 + row) * H_ + k0 + c4];
      float4 g = *(const float4*)&wg[(size_t)(n0 + row) * H_ + k0 + c4];
      us4 av = { f2bf(a.x), f2bf(a.y), f2bf(a.z), f2bf(a.w) };
      us4 uv = { f2bf(u.x), f2bf(u.y), f2bf(u.z), f2bf(u.w) };
      us4 gv = { f2bf(g.x), f2bf(g.y), f2bf(g.z), f2bf(g.w) };
      *(us4*)&As[row * LDK + c4] = av;
      *(us4*)&Bu[row * LDK + c4] = uv;
      *(us4*)&Bg[row * LDK + c4] = gv;
    }
    __syncthreads();
    bf16x8 af[4], bu[4], bg[4];
#pragma unroll
    for (int mi = 0; mi < 4; mi++)
      af[mi] = *(const bf16x8*)&As[(wm + mi * 16 + rrow) * LDK + quad * 8];
#pragma unroll
    for (int ni = 0; ni < 4; ni++) {
      bu[ni] = *(const bf16x8*)&Bu[(wn + ni * 16 + rrow) * LDK + quad * 8];
      bg[ni] = *(const bf16x8*)&Bg[(wn + ni * 16 + rrow) * LDK + quad * 8];
    }
#pragma unroll
    for (int mi = 0; mi < 4; mi++)
#pragma unroll
      for (int ni = 0; ni < 4; ni++) {
        accU[mi][ni] = __builtin_amdgcn_mfma_f32_16x16x32_bf16(af[mi], bu[ni], accU[mi][ni], 0, 0, 0);
        accG[mi][ni] = __builtin_amdgcn_mfma_f32_16x16x32_bf16(af[mi], bg[ni], accG[mi][ni], 0, 0, 0);
      }
    __syncthreads();
  }
#pragma unroll
  for (int mi = 0; mi < 4; mi++)
#pragma unroll
    for (int ni = 0; ni < 4; ni++)
#pragma unroll
      for (int r = 0; r < 4; r++) {
        int row = wm + mi * 16 + quad * 4 + r;
        int col = wn + ni * 16 + rrow;
        float u = accU[mi][ni][r], g = accG[mi][ni][r];
        float sig = 1.0f / (1.0f + __expf(-g));
        hbuf[(size_t)(m0 + row) * I_ + n0 + col] = f2bf(u * g * sig * smask[row]);
      }
}

__global__ __launch_bounds__(256)
void mlp_down_fb(const unsigned short* __restrict__ hbuf,
                 const float* __restrict__ wd, float* __restrict__ out)
{
  __shared__ unsigned short As[TM * LDK];
  __shared__ unsigned short Bs[TN * LDK];
  const int tid = threadIdx.x;
  const int m0 = blockIdx.x * TM, n0 = blockIdx.y * TN;
  const int wave = tid >> 6, lane = tid & 63;
  const int quad = lane >> 4, rrow = lane & 15;
  const int wm = (wave & 1) * 64, wn = (wave >> 1) * 64;

  f32x4 acc[4][4];
  const f32x4 zero = {0.f, 0.f, 0.f, 0.f};
  for (int i = 0; i < 4; i++)
    for (int j = 0; j < 4; j++) acc[i][j] = zero;

  for (int k0 = 0; k0 < I_; k0 += BK) {
#pragma unroll
    for (int s = 0; s < 4; s++) {
      int idx = tid + s * 256, row = idx >> 3, c4 = (idx & 7) * 4;
      us4 av = *(const us4*)&hbuf[(size_t)(m0 + row) * I_ + k0 + c4];
      float4 b = *(const float4*)&wd[(size_t)(n0 + row) * I_ + k0 + c4];
      us4 bv = { f2bf(b.x), f2bf(b.y), f2bf(b.z), f2bf(b.w) };
      *(us4*)&As[row * LDK + c4] = av;
      *(us4*)&Bs[row * LDK + c4] = bv;
    }
    __syncthreads();
    bf16x8 af[4], bf[4];
#pragma unroll
    for (int mi = 0; mi < 4; mi++)
      af[mi] = *(const bf16x8*)&As[(wm + mi * 16 + rrow) * LDK + quad * 8];
#pragma unroll
    for (int ni = 0; ni < 4; ni++)
      bf[ni] = *(const bf16x8*)&Bs[(wn + ni * 16 + rrow) * LDK + quad * 8];
#pragma unroll
    for (int mi = 0; mi < 4; mi++)
#pragma unroll
      for (int ni = 0; ni < 4; ni++)
        acc[mi][ni] = __builtin_amdgcn_mfma_f32_16x16x32_bf16(af[mi], bf[ni], acc[mi][ni], 0, 0, 0);
    __syncthreads();
  }
#pragma unroll
  for (int mi = 0; mi < 4; mi++)
#pragma unroll
    for (int ni = 0; ni < 4; ni++)
#pragma unroll
      for (int r = 0; r < 4; r++) {
        int row = wm + mi * 16 + quad * 4 + r;
        int col = wn + ni * 16 + rrow;
        out[(size_t)(m0 + row) * H_ + n0 + col] = acc[mi][ni][r];
      }
}

// ---------------------------------------------------------------------------
extern "C" void kernel_launch(void* const* d_in, const int* in_sizes, int n_in,
                              void* d_out, int out_size, void* d_ws, size_t ws_size,
                              hipStream_t stream) {
  const float* hs  = (const float*)d_in[0];
  const float* wu  = (const float*)d_in[1];
  const float* wg  = (const float*)d_in[2];
  const float* wd  = (const float*)d_in[3];
  const int*   msk = (const int*)d_in[4];
  float* out = (float*)d_out;

  // workspace layout (bytes)
  const size_t SZ_H    = (size_t)M_ * I_ * 2;   // 90,177,536
  const size_t SZ_HS   = (size_t)M_ * H_ * 2;   // 33,554,432
  const size_t SZ_W    = (size_t)I_ * H_ * 2;   // 90,177,536
  const size_t NEED = SZ_H + SZ_HS + 3 * SZ_W;  // 394,264,576

  unsigned short* hbuf = (unsigned short*)d_ws;

  if (ws_size >= NEED) {
    unsigned short* hs16 = (unsigned short*)((char*)d_ws + SZ_H);
    unsigned short* wu16 = (unsigned short*)((char*)d_ws + SZ_H + SZ_HS);
    unsigned short* wg16 = (unsigned short*)((char*)d_ws + SZ_H + SZ_HS + SZ_W);
    unsigned short* wd16 = (unsigned short*)((char*)d_ws + SZ_H + SZ_HS + 2 * SZ_W);

    const int n8_hs = (M_ * H_) / 8;          // 2,097,152
    const int n8_w  = (int)((size_t)I_ * H_ / 8);  // 5,636,096
    cvt_bf16<<<(n8_hs + 255) / 256, 256, 0, stream>>>(hs, hs16, n8_hs);
    cvt_bf16<<<(n8_w + 255) / 256, 256, 0, stream>>>(wu, wu16, n8_w);
    cvt_bf16<<<(n8_w + 255) / 256, 256, 0, stream>>>(wg, wg16, n8_w);
    cvt_bf16<<<(n8_w + 255) / 256, 256, 0, stream>>>(wd, wd16, n8_w);

    dim3 g1(M_ / 128, I_ / 64);   // 32 x 172
    mlp_upgate2<<<g1, dim3(256), 0, stream>>>(hs16, wu16, wg16, msk, hbuf);

    dim3 g2(M_ / 128, H_ / 128);  // 32 x 32
    mlp_down2<<<g2, dim3(256), 0, stream>>>(hbuf, wd16, out);
  } else {
    dim3 g1(M_ / TM, I_ / TN);
    mlp_upgate_fb<<<g1, dim3(256), 0, stream>>>(hs, wu, wg, msk, hbuf);
    dim3 g2(M_ / TM, H_ / TN);
    mlp_down_fb<<<g2, dim3(256), 0, stream>>>(hbuf, wd, out);
  }
}

// Round 3
// 1924.216 us; speedup vs baseline: 1.9244x; 1.0145x over previous
//
#include <hip/hip_runtime.h>
#include <stdint.h>

// Problem dims (fixed by reference)
#define MB_ 2
#define LL_ 2048
#define M_ (MB_*LL_)   // 4096 tokens
#define H_ 4096
#define I_ 11008

typedef __attribute__((ext_vector_type(8))) short bf16x8;
typedef __attribute__((ext_vector_type(4))) float f32x4;
typedef __attribute__((ext_vector_type(4))) unsigned short us4;

__device__ __forceinline__ unsigned short f2bf(float f) {
  union { float f; unsigned int u; } v; v.f = f;
  unsigned int r = v.u + 0x7FFFu + ((v.u >> 16) & 1u);  // RNE
  return (unsigned short)(r >> 16);
}

__device__ __forceinline__ void gl2lds16(const void* g, void* l) {
  __builtin_amdgcn_global_load_lds(
      (const __attribute__((address_space(1))) void*)g,
      (__attribute__((address_space(3))) void*)l, 16, 0, 0);
}

// ---------------------------------------------------------------------------
// Compact active token indices. Single block. idx[0..cnt) = active tokens,
// idx[cnt..M_) = 0 (padding so downstream gathers stay in-bounds).
// ---------------------------------------------------------------------------
__global__ __launch_bounds__(256)
void compact_mask(const int* __restrict__ mask, int* __restrict__ idx,
                  int* __restrict__ cnt) {
  __shared__ int lcnt[256];
  __shared__ int loff[256];
  __shared__ int stot;
  const int t = threadIdx.x;
  const int base = t * 16;
  int c = 0;
#pragma unroll
  for (int j = 0; j < 16; j++) c += (mask[base + j] != 0);
  lcnt[t] = c;
  __syncthreads();
  if (t == 0) {
    int s = 0;
    for (int i = 0; i < 256; i++) { loff[i] = s; s += lcnt[i]; }
    stot = s;
    cnt[0] = s;
  }
  __syncthreads();
  int o = loff[t];
#pragma unroll
  for (int j = 0; j < 16; j++)
    if (mask[base + j] != 0) idx[o++] = base + j;
  const int total = stot;
  for (int s = total + t; s < M_; s += 256) idx[s] = 0;
}

// ---------------------------------------------------------------------------
// fp32 -> bf16 bulk conversion (8 elems / thread)
// ---------------------------------------------------------------------------
__global__ __launch_bounds__(256)
void cvt_bf16(const float* __restrict__ src, unsigned short* __restrict__ dst, int n8) {
  int i = blockIdx.x * blockDim.x + threadIdx.x;
  if (i >= n8) return;
  const float4* s = (const float4*)src + (size_t)i * 2;
  float4 a = s[0], b = s[1];
  us4 lo = { f2bf(a.x), f2bf(a.y), f2bf(a.z), f2bf(a.w) };
  us4 hi = { f2bf(b.x), f2bf(b.y), f2bf(b.z), f2bf(b.w) };
  us4* d = (us4*)dst + (size_t)i * 2;
  d[0] = lo; d[1] = hi;
}

// ---------------------------------------------------------------------------
// Gather active hs rows -> compacted bf16 [slot, H].  grid = (M_, H_/2048)
// ---------------------------------------------------------------------------
__global__ __launch_bounds__(256)
void gather_cvt_hs(const float* __restrict__ hs, const int* __restrict__ idx,
                   unsigned short* __restrict__ dst) {
  const int slot = blockIdx.x;
  const int row  = idx[slot];
  const int col  = (blockIdx.y * 256 + threadIdx.x) * 8;
  const float4* s = (const float4*)(hs + (size_t)row * H_ + col);
  float4 a = s[0], b = s[1];
  us4 lo = { f2bf(a.x), f2bf(a.y), f2bf(a.z), f2bf(a.w) };
  us4 hi = { f2bf(b.x), f2bf(b.y), f2bf(b.z), f2bf(b.w) };
  unsigned short* d = dst + (size_t)slot * H_ + col;
  *(us4*)d = lo;
  *(us4*)(d + 4) = hi;
}

// ---------------------------------------------------------------------------
// GEMM1 compacted: h[slot,i] = up * silu(gate) for active slots (mask==1).
// A = hs16c [Mc,H] bf16 (compacted); Wu,Wg bf16 [I,H]. Tile M=128,N=64 dual.
// ---------------------------------------------------------------------------
__global__ __launch_bounds__(256)
void mlp_upgate3(const unsigned short* __restrict__ hs16c,
                 const unsigned short* __restrict__ wu16,
                 const unsigned short* __restrict__ wg16,
                 const int* __restrict__ cnt,
                 unsigned short* __restrict__ hbuf)
{
  const int mtiles = (cnt[0] + 127) >> 7;
  if ((int)blockIdx.x >= mtiles) return;

  __shared__ unsigned short As[128 * 32];
  __shared__ unsigned short Bu[64 * 32];
  __shared__ unsigned short Bg[64 * 32];

  const int tid  = threadIdx.x;
  const int m0   = blockIdx.x * 128;
  const int n0   = blockIdx.y * 64;
  const int w    = tid >> 6;
  const int lane = tid & 63;
  const int quad = lane >> 4;
  const int rrow = lane & 15;
  const int wm   = (w & 1) * 64;
  const int wn   = (w >> 1) * 32;

  const int lr = lane >> 2;
  const int lc = (lane & 3) * 8;
  const unsigned short* pa0 = hs16c + (size_t)(m0 + w * 32 + lr) * H_ + lc;
  const unsigned short* pa1 = pa0 + (size_t)16 * H_;
  const unsigned short* pu  = wu16 + (size_t)(n0 + w * 16 + lr) * H_ + lc;
  const unsigned short* pg  = wg16 + (size_t)(n0 + w * 16 + lr) * H_ + lc;
  unsigned short* la0 = &As[(w * 32) * 32];
  unsigned short* la1 = &As[(w * 32 + 16) * 32];
  unsigned short* lu  = &Bu[(w * 16) * 32];
  unsigned short* lg  = &Bg[(w * 16) * 32];

  f32x4 accU[4][2], accG[4][2];
  const f32x4 zero = {0.f, 0.f, 0.f, 0.f};
  for (int i = 0; i < 4; i++)
    for (int j = 0; j < 2; j++) { accU[i][j] = zero; accG[i][j] = zero; }

  for (int k0 = 0; k0 < H_; k0 += 32) {
    gl2lds16(pa0 + k0, la0);
    gl2lds16(pa1 + k0, la1);
    gl2lds16(pu + k0, lu);
    gl2lds16(pg + k0, lg);
    __syncthreads();

    bf16x8 af[4], bu[2], bg[2];
#pragma unroll
    for (int mi = 0; mi < 4; mi++)
      af[mi] = *(const bf16x8*)&As[(wm + mi * 16 + rrow) * 32 + quad * 8];
#pragma unroll
    for (int ni = 0; ni < 2; ni++) {
      bu[ni] = *(const bf16x8*)&Bu[(wn + ni * 16 + rrow) * 32 + quad * 8];
      bg[ni] = *(const bf16x8*)&Bg[(wn + ni * 16 + rrow) * 32 + quad * 8];
    }
#pragma unroll
    for (int mi = 0; mi < 4; mi++)
#pragma unroll
      for (int ni = 0; ni < 2; ni++) {
        accU[mi][ni] = __builtin_amdgcn_mfma_f32_16x16x32_bf16(af[mi], bu[ni], accU[mi][ni], 0, 0, 0);
        accG[mi][ni] = __builtin_amdgcn_mfma_f32_16x16x32_bf16(af[mi], bg[ni], accG[mi][ni], 0, 0, 0);
      }
    __syncthreads();
  }

  // epilogue: C/D layout col=lane&15, row=quad*4+reg (verified m89/m91)
#pragma unroll
  for (int mi = 0; mi < 4; mi++)
#pragma unroll
    for (int ni = 0; ni < 2; ni++)
#pragma unroll
      for (int r = 0; r < 4; r++) {
        int row = wm + mi * 16 + quad * 4 + r;
        int col = wn + ni * 16 + rrow;
        float u = accU[mi][ni][r];
        float g = accG[mi][ni][r];
        float sig = 1.0f / (1.0f + __expf(-g));
        hbuf[(size_t)(m0 + row) * I_ + n0 + col] = f2bf(u * g * sig);
      }
}

// ---------------------------------------------------------------------------
// GEMM2 compacted: out[idx[slot],n] = sum_i h[slot,i]*wd[n,i]. Scatter rows.
// Tile 128x128, BK=32.
// ---------------------------------------------------------------------------
__global__ __launch_bounds__(256)
void mlp_down3(const unsigned short* __restrict__ hbuf,
               const unsigned short* __restrict__ wd16,
               const int* __restrict__ idx, const int* __restrict__ cnt,
               float* __restrict__ out)
{
  const int count  = cnt[0];
  const int mtiles = (count + 127) >> 7;
  if ((int)blockIdx.x >= mtiles) return;

  __shared__ unsigned short As[128 * 32];
  __shared__ unsigned short Bs[128 * 32];

  const int tid  = threadIdx.x;
  const int m0   = blockIdx.x * 128;
  const int n0   = blockIdx.y * 128;
  const int w    = tid >> 6;
  const int lane = tid & 63;
  const int quad = lane >> 4;
  const int rrow = lane & 15;
  const int wm   = (w & 1) * 64;
  const int wn   = (w >> 1) * 64;

  const int lr = lane >> 2;
  const int lc = (lane & 3) * 8;
  const unsigned short* pa0 = hbuf + (size_t)(m0 + w * 32 + lr) * I_ + lc;
  const unsigned short* pa1 = pa0 + (size_t)16 * I_;
  const unsigned short* pb0 = wd16 + (size_t)(n0 + w * 32 + lr) * I_ + lc;
  const unsigned short* pb1 = pb0 + (size_t)16 * I_;
  unsigned short* la0 = &As[(w * 32) * 32];
  unsigned short* la1 = &As[(w * 32 + 16) * 32];
  unsigned short* lb0 = &Bs[(w * 32) * 32];
  unsigned short* lb1 = &Bs[(w * 32 + 16) * 32];

  f32x4 acc[4][4];
  const f32x4 zero = {0.f, 0.f, 0.f, 0.f};
  for (int i = 0; i < 4; i++)
    for (int j = 0; j < 4; j++) acc[i][j] = zero;

  for (int k0 = 0; k0 < I_; k0 += 32) {
    gl2lds16(pa0 + k0, la0);
    gl2lds16(pa1 + k0, la1);
    gl2lds16(pb0 + k0, lb0);
    gl2lds16(pb1 + k0, lb1);
    __syncthreads();

    bf16x8 af[4], bf[4];
#pragma unroll
    for (int mi = 0; mi < 4; mi++)
      af[mi] = *(const bf16x8*)&As[(wm + mi * 16 + rrow) * 32 + quad * 8];
#pragma unroll
    for (int ni = 0; ni < 4; ni++)
      bf[ni] = *(const bf16x8*)&Bs[(wn + ni * 16 + rrow) * 32 + quad * 8];
#pragma unroll
    for (int mi = 0; mi < 4; mi++)
#pragma unroll
      for (int ni = 0; ni < 4; ni++)
        acc[mi][ni] = __builtin_amdgcn_mfma_f32_16x16x32_bf16(af[mi], bf[ni], acc[mi][ni], 0, 0, 0);
    __syncthreads();
  }

#pragma unroll
  for (int mi = 0; mi < 4; mi++)
#pragma unroll
    for (int r = 0; r < 4; r++) {
      int row  = wm + mi * 16 + quad * 4 + r;
      int slot = m0 + row;
      if (slot < count) {
        int tok = idx[slot];
        float* orow = out + (size_t)tok * H_ + n0;
#pragma unroll
        for (int ni = 0; ni < 4; ni++)
          orow[wn + ni * 16 + rrow] = acc[mi][ni][r];
      }
    }
}

// ===========================================================================
// Fallback path (round-1 kernels) if ws_size is too small.
// ===========================================================================
#define TM 128
#define TN 128
#define BK 32
#define LDK 40

__global__ __launch_bounds__(256)
void mlp_upgate_fb(const float* __restrict__ hs, const float* __restrict__ wu,
                   const float* __restrict__ wg, const int* __restrict__ mask,
                   unsigned short* __restrict__ hbuf)
{
  __shared__ unsigned short As[TM * LDK];
  __shared__ unsigned short Bu[TN * LDK];
  __shared__ unsigned short Bg[TN * LDK];
  __shared__ float smask[TM];

  const int tid = threadIdx.x;
  const int m0 = blockIdx.x * TM;
  const int n0 = blockIdx.y * TN;
  if (tid < TM) smask[tid] = (float)mask[m0 + tid];
  const int wave = tid >> 6, lane = tid & 63;
  const int quad = lane >> 4, rrow = lane & 15;
  const int wm = (wave & 1) * 64, wn = (wave >> 1) * 64;

  f32x4 accU[4][4], accG[4][4];
  const f32x4 zero = {0.f, 0.f, 0.f, 0.f};
  for (int i = 0; i < 4; i++)
    for (int j = 0; j < 4; j++) { accU[i][j] = zero; accG[i][j] = zero; }

  for (int k0 = 0; k0 < H_; k0 += BK) {
#pragma unroll
    for (int s = 0; s < 4; s++) {
      int idx2 = tid + s * 256, row = idx2 >> 3, c4 = (idx2 & 7) * 4;
      float4 a = *(const float4*)&hs[(size_t)(m0 + row) * H_ + k0 + c4];
      float4 u = *(const float4*)&wu[(size_t)(n0 + row) * H_ + k0 + c4];
      float4 g = *(const float4*)&wg[(size_t)(n0 + row) * H_ + k0 + c4];
      us4 av = { f2bf(a.x), f2bf(a.y), f2bf(a.z), f2bf(a.w) };
      us4 uv = { f2bf(u.x), f2bf(u.y), f2bf(u.z), f2bf(u.w) };
      us4 gv = { f2bf(g.x), f2bf(g.y), f2bf(g.z), f2bf(g.w) };
      *(us4*)&As[row * LDK + c4] = av;
      *(us4*)&Bu[row * LDK + c4] = uv;
      *(us4*)&Bg[row * LDK + c4] = gv;
    }
    __syncthreads();
    bf16x8 af[4], bu[4], bg[4];
#pragma unroll
    for (int mi = 0; mi < 4; mi++)
      af[mi] = *(const bf16x8*)&As[(wm + mi * 16 + rrow) * LDK + quad * 8];
#pragma unroll
    for (int ni = 0; ni < 4; ni++) {
      bu[ni] = *(const bf16x8*)&Bu[(wn + ni * 16 + rrow) * LDK + quad * 8];
      bg[ni] = *(const bf16x8*)&Bg[(wn + ni * 16 + rrow) * LDK + quad * 8];
    }
#pragma unroll
    for (int mi = 0; mi < 4; mi++)
#pragma unroll
      for (int ni = 0; ni < 4; ni++) {
        accU[mi][ni] = __builtin_amdgcn_mfma_f32_16x16x32_bf16(af[mi], bu[ni], accU[mi][ni], 0, 0, 0);
        accG[mi][ni] = __builtin_amdgcn_mfma_f32_16x16x32_bf16(af[mi], bg[ni], accG[mi][ni], 0, 0, 0);
      }
    __syncthreads();
  }
#pragma unroll
  for (int mi = 0; mi < 4; mi++)
#pragma unroll
    for (int ni = 0; ni < 4; ni++)
#pragma unroll
      for (int r = 0; r < 4; r++) {
        int row = wm + mi * 16 + quad * 4 + r;
        int col = wn + ni * 16 + rrow;
        float u = accU[mi][ni][r], g = accG[mi][ni][r];
        float sig = 1.0f / (1.0f + __expf(-g));
        hbuf[(size_t)(m0 + row) * I_ + n0 + col] = f2bf(u * g * sig * smask[row]);
      }
}

__global__ __launch_bounds__(256)
void mlp_down_fb(const unsigned short* __restrict__ hbuf,
                 const float* __restrict__ wd, float* __restrict__ out)
{
  __shared__ unsigned short As[TM * LDK];
  __shared__ unsigned short Bs[TN * LDK];
  const int tid = threadIdx.x;
  const int m0 = blockIdx.x * TM, n0 = blockIdx.y * TN;
  const int wave = tid >> 6, lane = tid & 63;
  const int quad = lane >> 4, rrow = lane & 15;
  const int wm = (wave & 1) * 64, wn = (wave >> 1) * 64;

  f32x4 acc[4][4];
  const f32x4 zero = {0.f, 0.f, 0.f, 0.f};
  for (int i = 0; i < 4; i++)
    for (int j = 0; j < 4; j++) acc[i][j] = zero;

  for (int k0 = 0; k0 < I_; k0 += BK) {
#pragma unroll
    for (int s = 0; s < 4; s++) {
      int idx2 = tid + s * 256, row = idx2 >> 3, c4 = (idx2 & 7) * 4;
      us4 av = *(const us4*)&hbuf[(size_t)(m0 + row) * I_ + k0 + c4];
      float4 b = *(const float4*)&wd[(size_t)(n0 + row) * I_ + k0 + c4];
      us4 bv = { f2bf(b.x), f2bf(b.y), f2bf(b.z), f2bf(b.w) };
      *(us4*)&As[row * LDK + c4] = av;
      *(us4*)&Bs[row * LDK + c4] = bv;
    }
    __syncthreads();
    bf16x8 af[4], bf[4];
#pragma unroll
    for (int mi = 0; mi < 4; mi++)
      af[mi] = *(const bf16x8*)&As[(wm + mi * 16 + rrow) * LDK + quad * 8];
#pragma unroll
    for (int ni = 0; ni < 4; ni++)
      bf[ni] = *(const bf16x8*)&Bs[(wn + ni * 16 + rrow) * LDK + quad * 8];
#pragma unroll
    for (int mi = 0; mi < 4; mi++)
#pragma unroll
      for (int ni = 0; ni < 4; ni++)
        acc[mi][ni] = __builtin_amdgcn_mfma_f32_16x16x32_bf16(af[mi], bf[ni], acc[mi][ni], 0, 0, 0);
    __syncthreads();
  }
#pragma unroll
  for (int mi = 0; mi < 4; mi++)
#pragma unroll
    for (int ni = 0; ni < 4; ni++)
#pragma unroll
      for (int r = 0; r < 4; r++) {
        int row = wm + mi * 16 + quad * 4 + r;
        int col = wn + ni * 16 + rrow;
        out[(size_t)(m0 + row) * H_ + n0 + col] = acc[mi][ni][r];
      }
}

// ---------------------------------------------------------------------------
extern "C" void kernel_launch(void* const* d_in, const int* in_sizes, int n_in,
                              void* d_out, int out_size, void* d_ws, size_t ws_size,
                              hipStream_t stream) {
  const float* hs  = (const float*)d_in[0];
  const float* wu  = (const float*)d_in[1];
  const float* wg  = (const float*)d_in[2];
  const float* wd  = (const float*)d_in[3];
  const int*   msk = (const int*)d_in[4];
  float* out = (float*)d_out;

  // workspace layout (bytes)
  const size_t SZ_H  = (size_t)M_ * I_ * 2;   // 90,177,536  compacted h (bf16)
  const size_t SZ_HS = (size_t)M_ * H_ * 2;   // 33,554,432  compacted hs (bf16)
  const size_t SZ_W  = (size_t)I_ * H_ * 2;   // 90,177,536  per weight (bf16)
  const size_t SZ_IDX = (size_t)M_ * 4 + 64;  // idx + cnt
  const size_t NEED = SZ_H + SZ_HS + 3 * SZ_W + SZ_IDX;

  unsigned short* hbuf = (unsigned short*)d_ws;

  if (ws_size >= NEED) {
    char* p = (char*)d_ws;
    unsigned short* hs16c = (unsigned short*)(p + SZ_H);
    unsigned short* wu16  = (unsigned short*)(p + SZ_H + SZ_HS);
    unsigned short* wg16  = (unsigned short*)(p + SZ_H + SZ_HS + SZ_W);
    unsigned short* wd16  = (unsigned short*)(p + SZ_H + SZ_HS + 2 * SZ_W);
    int* idx = (int*)(p + SZ_H + SZ_HS + 3 * SZ_W);
    int* cnt = idx + M_;

    // zero output so masked token rows are exactly 0
    hipMemsetAsync(out, 0, (size_t)out_size * sizeof(float), stream);

    compact_mask<<<1, 256, 0, stream>>>(msk, idx, cnt);
    gather_cvt_hs<<<dim3(M_, H_ / 2048), 256, 0, stream>>>(hs, idx, hs16c);

    const int n8_w = (int)((size_t)I_ * H_ / 8);  // 5,636,096
    cvt_bf16<<<(n8_w + 255) / 256, 256, 0, stream>>>(wu, wu16, n8_w);
    cvt_bf16<<<(n8_w + 255) / 256, 256, 0, stream>>>(wg, wg16, n8_w);
    cvt_bf16<<<(n8_w + 255) / 256, 256, 0, stream>>>(wd, wd16, n8_w);

    dim3 g1(M_ / 128, I_ / 64);   // 32 x 172 (m-tiles beyond active count exit)
    mlp_upgate3<<<g1, dim3(256), 0, stream>>>(hs16c, wu16, wg16, cnt, hbuf);

    dim3 g2(M_ / 128, H_ / 128);  // 32 x 32
    mlp_down3<<<g2, dim3(256), 0, stream>>>(hbuf, wd16, idx, cnt, out);
  } else {
    dim3 g1(M_ / TM, I_ / TN);
    mlp_upgate_fb<<<g1, dim3(256), 0, stream>>>(hs, wu, wg, msk, hbuf);
    dim3 g2(M_ / TM, H_ / TN);
    mlp_down_fb<<<g2, dim3(256), 0, stream>>>(hbuf, wd, out);
  }
}